// Round 5
// baseline (3111.977 us; speedup 1.0000x reference)
//
#include <hip/hip_runtime.h>
#include <cstdint>

// ---- bf16 pack/unpack helpers (RNE) ----
__device__ inline unsigned int bfpack2(float a, float b) {
  unsigned int ua = __float_as_uint(a), ub = __float_as_uint(b);
  ua += 0x7FFFu + ((ua >> 16) & 1u);
  ub += 0x7FFFu + ((ub >> 16) & 1u);
  return (ua >> 16) | (ub & 0xFFFF0000u);
}
__device__ inline float bflo(unsigned int u) { return __uint_as_float(u << 16); }
__device__ inline float bfhi(unsigned int u) { return __uint_as_float(u & 0xFFFF0000u); }

// ---------------- degree histograms (dst for GCN norm, src for edge sort) ----------------
__global__ __launch_bounds__(256) void pre_kernel(const int* __restrict__ src,
                                                  const int* __restrict__ dst,
                                                  int* __restrict__ deg,
                                                  int* __restrict__ deg2, int nE) {
  int e = blockIdx.x * 256 + threadIdx.x;
  if (e < nE) {
    atomicAdd(&deg[dst[e]], 1);
    atomicAdd(&deg2[src[e]], 1);
  }
}

__global__ __launch_bounds__(256) void dinv_kernel(const int* __restrict__ deg,
                                                   float* __restrict__ dinv, int n) {
  int i = blockIdx.x * 256 + threadIdx.x;
  if (i < n) dinv[i] = rsqrtf((float)deg[i] + 1.0f);
}

// ---------------- exclusive scan (3 kernels) ----------------
__global__ __launch_bounds__(256) void scan1_kernel(const int* __restrict__ deg,
                                                    int* __restrict__ rp,
                                                    int* __restrict__ part, int n) {
  __shared__ int sh[256];
  int b = blockIdx.x, t = threadIdx.x;
  int base = b * 1024 + t * 4;
  int v0 = (base + 0 < n) ? deg[base + 0] : 0;
  int v1 = (base + 1 < n) ? deg[base + 1] : 0;
  int v2 = (base + 2 < n) ? deg[base + 2] : 0;
  int v3 = (base + 3 < n) ? deg[base + 3] : 0;
  int ts = v0 + v1 + v2 + v3;
  sh[t] = ts;
  __syncthreads();
  for (int off = 1; off < 256; off <<= 1) {
    int x = (t >= off) ? sh[t - off] : 0;
    __syncthreads();
    sh[t] += x;
    __syncthreads();
  }
  int excl = sh[t] - ts;
  if (t == 255) part[b] = sh[255];
  if (base + 0 < n) rp[base + 0] = excl;
  if (base + 1 < n) rp[base + 1] = excl + v0;
  if (base + 2 < n) rp[base + 2] = excl + v0 + v1;
  if (base + 3 < n) rp[base + 3] = excl + v0 + v1 + v2;
}

__global__ void scan2_kernel(int* part, int* rp, int nb, int n) {
  if (blockIdx.x == 0 && threadIdx.x == 0) {
    int run = 0;
    for (int i = 0; i < nb; ++i) { int v = part[i]; part[i] = run; run += v; }
    rp[n] = run;
  }
}

__global__ __launch_bounds__(256) void scan3_kernel(int* __restrict__ rp,
                                                    const int* __restrict__ part,
                                                    int* __restrict__ cursor, int n) {
  int i = blockIdx.x * 256 + threadIdx.x;
  if (i < n) {
    int v = rp[i] + part[i >> 10];
    rp[i] = v;
    cursor[i] = v;
  }
}

// ---------------- CSR placement: dst-CSR (srcs+wgt per node) + src-ordered edge list ----------------
__global__ __launch_bounds__(256) void place_kernel(const int* __restrict__ src,
                                                    const int* __restrict__ dst,
                                                    const int* __restrict__ batch,
                                                    const float* __restrict__ dinv,
                                                    int* __restrict__ cursor,
                                                    int* __restrict__ cursor2,
                                                    int* __restrict__ ssort,
                                                    float* __restrict__ wgtv,
                                                    unsigned int* __restrict__ epk, int nE) {
  int e = blockIdx.x * 256 + threadIdx.x;
  if (e < nE) {
    int s = src[e];
    int d = dst[e];
    int p1 = atomicAdd(&cursor[d], 1);
    ssort[p1] = s;
    wgtv[p1] = dinv[s] * dinv[d];
    int g = batch[s];
    int p2 = atomicAdd(&cursor2[s], 1);
    epk[p2] = ((unsigned int)g << 21) | (unsigned int)e;
  }
}

// ---------------- dense GEMM: hpk[N,64] = pack_bf16(act(A)[N,128] @ W[128,128]) ----------------
// Output written ONLY as packed bf162: entry e of a row holds channels (e, e+64).
// FUSED applies y = relu(a*scale+shift) while staging A (previous layer's BN+ReLU).
template <bool FUSED>
__global__ __launch_bounds__(256) void gemm128_kernel(const float* __restrict__ A,
                                                      const float* __restrict__ W,
                                                      const float* __restrict__ scale,
                                                      const float* __restrict__ shift,
                                                      unsigned int* __restrict__ hpk,
                                                      int nrows) {
  extern __shared__ float lds[];
  float* Ws = lds;             // 128*128 floats
  float* xs = lds + 128 * 128; // 16*128 floats
  const int t = threadIdx.x;
  for (int i = t; i < (128 * 128) / 4; i += 256)
    reinterpret_cast<float4*>(Ws)[i] = reinterpret_cast<const float4*>(W)[i];
  const int wave = t >> 6, lane = t & 63;
  for (int rb = blockIdx.x * 16; rb < nrows; rb += gridDim.x * 16) {
    int nr = min(16, nrows - rb);
    __syncthreads();
    for (int i = t; i < nr * 32; i += 256) {
      float4 v = reinterpret_cast<const float4*>(A + (size_t)rb * 128)[i];
      if (FUSED) {
        float4 sc4 = reinterpret_cast<const float4*>(scale)[i & 31];
        float4 sh4 = reinterpret_cast<const float4*>(shift)[i & 31];
        v.x = fmaxf(fmaf(v.x, sc4.x, sh4.x), 0.f);
        v.y = fmaxf(fmaf(v.y, sc4.y, sh4.y), 0.f);
        v.z = fmaxf(fmaf(v.z, sc4.z, sh4.z), 0.f);
        v.w = fmaxf(fmaf(v.w, sc4.w, sh4.w), 0.f);
      }
      reinterpret_cast<float4*>(xs)[i] = v;
    }
    __syncthreads();
    float acc[4][2] = {{0.f, 0.f}, {0.f, 0.f}, {0.f, 0.f}, {0.f, 0.f}};
    const float* xw = xs + wave * 4 * 128;
#pragma unroll 4
    for (int k = 0; k < 128; ++k) {
      float w0 = Ws[k * 128 + lane];
      float w1 = Ws[k * 128 + 64 + lane];
#pragma unroll
      for (int r = 0; r < 4; ++r) {
        float a = xw[r * 128 + k];
        acc[r][0] = fmaf(a, w0, acc[r][0]);
        acc[r][1] = fmaf(a, w1, acc[r][1]);
      }
    }
#pragma unroll
    for (int r = 0; r < 4; ++r) {
      int row = rb + wave * 4 + r;
      if (row < nrows)
        hpk[(size_t)row * 64 + lane] = bfpack2(acc[r][0], acc[r][1]);
    }
  }
}

// ---------------- SpMM + self-loop + bias, with BN stats ----------------
// ONE node per wave; all 4 sixteen-lane quarters work the SAME node's edge list
// (quarter q takes edges beg+q, beg+q+4, ...; shared bounds -> no divergence).
// Lane m of a quarter reads uint4 = packed entries [4m,4m+4) = channels
// {4m..4m+3, 64+4m..+3}; one wave iteration has 8 row-gathers (2 KB) in flight.
__global__ __launch_bounds__(256) void spmm_kernel(const unsigned int* __restrict__ hpk,
                                                   const float* __restrict__ dinv,
                                                   const int* __restrict__ rp,
                                                   const int* __restrict__ srcs,
                                                   const float* __restrict__ wgtv,
                                                   const float* __restrict__ bias,
                                                   float* __restrict__ outp,
                                                   float* __restrict__ bnsum,
                                                   float* __restrict__ bnsq, int nN) {
  const int lane = threadIdx.x & 63;
  const int m = lane & 15;
  const int qsel = lane >> 4;
  const int cL = 4 * m;       // low channel base (also u32 entry base)
  const int cH = 64 + 4 * m;  // high channel base
  const int wid = (blockIdx.x * blockDim.x + threadIdx.x) >> 6;
  const int nw = (gridDim.x * blockDim.x) >> 6;
  float4 bL = *reinterpret_cast<const float4*>(bias + cL);
  float4 bH = *reinterpret_cast<const float4*>(bias + cH);
  float sL[4] = {0.f, 0.f, 0.f, 0.f}, sH[4] = {0.f, 0.f, 0.f, 0.f};
  float qL[4] = {0.f, 0.f, 0.f, 0.f}, qH[4] = {0.f, 0.f, 0.f, 0.f};
  for (int n = wid; n < nN; n += nw) {
    int beg = rp[n], end = rp[n + 1];
    float aL[4] = {0.f, 0.f, 0.f, 0.f}, aH[4] = {0.f, 0.f, 0.f, 0.f};
    int j = beg + qsel;
    // unrolled x2: edges j and j+4 (8 edges per wave iteration)
    for (; j + 4 < end; j += 8) {
      int s0 = srcs[j], s1 = srcs[j + 4];
      float w0 = wgtv[j], w1 = wgtv[j + 4];
      uint4 p0 = *reinterpret_cast<const uint4*>(hpk + (size_t)s0 * 64 + cL);
      uint4 p1 = *reinterpret_cast<const uint4*>(hpk + (size_t)s1 * 64 + cL);
      aL[0] = fmaf(w0, bflo(p0.x), aL[0]); aH[0] = fmaf(w0, bfhi(p0.x), aH[0]);
      aL[1] = fmaf(w0, bflo(p0.y), aL[1]); aH[1] = fmaf(w0, bfhi(p0.y), aH[1]);
      aL[2] = fmaf(w0, bflo(p0.z), aL[2]); aH[2] = fmaf(w0, bfhi(p0.z), aH[2]);
      aL[3] = fmaf(w0, bflo(p0.w), aL[3]); aH[3] = fmaf(w0, bfhi(p0.w), aH[3]);
      aL[0] = fmaf(w1, bflo(p1.x), aL[0]); aH[0] = fmaf(w1, bfhi(p1.x), aH[0]);
      aL[1] = fmaf(w1, bflo(p1.y), aL[1]); aH[1] = fmaf(w1, bfhi(p1.y), aH[1]);
      aL[2] = fmaf(w1, bflo(p1.z), aL[2]); aH[2] = fmaf(w1, bfhi(p1.z), aH[2]);
      aL[3] = fmaf(w1, bflo(p1.w), aL[3]); aH[3] = fmaf(w1, bfhi(p1.w), aH[3]);
    }
    if (j < end) {
      int s0 = srcs[j];
      float w0 = wgtv[j];
      uint4 p0 = *reinterpret_cast<const uint4*>(hpk + (size_t)s0 * 64 + cL);
      aL[0] = fmaf(w0, bflo(p0.x), aL[0]); aH[0] = fmaf(w0, bfhi(p0.x), aH[0]);
      aL[1] = fmaf(w0, bflo(p0.y), aL[1]); aH[1] = fmaf(w0, bfhi(p0.y), aH[1]);
      aL[2] = fmaf(w0, bflo(p0.z), aL[2]); aH[2] = fmaf(w0, bfhi(p0.z), aH[2]);
      aL[3] = fmaf(w0, bflo(p0.w), aL[3]); aH[3] = fmaf(w0, bfhi(p0.w), aH[3]);
    }
    // cross-quarter reduce (lanes m, m+16, m+32, m+48 hold same channels)
#pragma unroll
    for (int t = 0; t < 4; ++t) {
      aL[t] += __shfl_xor(aL[t], 16); aL[t] += __shfl_xor(aL[t], 32);
      aH[t] += __shfl_xor(aH[t], 16); aH[t] += __shfl_xor(aH[t], 32);
    }
    if (qsel == 0) {
      float dn = dinv[n];
      float sw = dn * dn;
      uint4 pn = *reinterpret_cast<const uint4*>(hpk + (size_t)n * 64 + cL);
      float oL0 = fmaf(bflo(pn.x), sw, aL[0]) + bL.x;
      float oL1 = fmaf(bflo(pn.y), sw, aL[1]) + bL.y;
      float oL2 = fmaf(bflo(pn.z), sw, aL[2]) + bL.z;
      float oL3 = fmaf(bflo(pn.w), sw, aL[3]) + bL.w;
      float oH0 = fmaf(bfhi(pn.x), sw, aH[0]) + bH.x;
      float oH1 = fmaf(bfhi(pn.y), sw, aH[1]) + bH.y;
      float oH2 = fmaf(bfhi(pn.z), sw, aH[2]) + bH.z;
      float oH3 = fmaf(bfhi(pn.w), sw, aH[3]) + bH.w;
      float4 vL; vL.x = oL0; vL.y = oL1; vL.z = oL2; vL.w = oL3;
      float4 vH; vH.x = oH0; vH.y = oH1; vH.z = oH2; vH.w = oH3;
      *reinterpret_cast<float4*>(outp + (size_t)n * 128 + cL) = vL;
      *reinterpret_cast<float4*>(outp + (size_t)n * 128 + cH) = vH;
      sL[0] += oL0; sL[1] += oL1; sL[2] += oL2; sL[3] += oL3;
      sH[0] += oH0; sH[1] += oH1; sH[2] += oH2; sH[3] += oH3;
      qL[0] = fmaf(oL0, oL0, qL[0]); qL[1] = fmaf(oL1, oL1, qL[1]);
      qL[2] = fmaf(oL2, oL2, qL[2]); qL[3] = fmaf(oL3, oL3, qL[3]);
      qH[0] = fmaf(oH0, oH0, qH[0]); qH[1] = fmaf(oH1, oH1, qH[1]);
      qH[2] = fmaf(oH2, oH2, qH[2]); qH[3] = fmaf(oH3, oH3, qH[3]);
    }
  }
  if (lane < 16) {
#pragma unroll
    for (int t = 0; t < 4; ++t) {
      atomicAdd(&bnsum[cL + t], sL[t]);
      atomicAdd(&bnsum[cH + t], sH[t]);
      atomicAdd(&bnsq[cL + t], qL[t]);
      atomicAdd(&bnsq[cH + t], qH[t]);
    }
  }
}

// ---------------- BN finalize ----------------
__global__ void bnfin_kernel(const float* __restrict__ sum, const float* __restrict__ sq,
                             const float* __restrict__ gamma, const float* __restrict__ beta,
                             float* __restrict__ scale, float* __restrict__ shift,
                             float invN) {
  int c = threadIdx.x;
  float mu = sum[c] * invN;
  float var = sq[c] * invN - mu * mu;
  float sc = gamma[c] * rsqrtf(var + 1e-5f);
  scale[c] = sc;
  shift[c] = beta[c] - mu * sc;
}

// ---------------- graph mean pool, fused BN+ReLU (batch_idx sorted -> run-length) ----------------
__global__ __launch_bounds__(256) void pool_kernel(const float* __restrict__ h,
                                                   const int* __restrict__ batch,
                                                   const float* __restrict__ scale,
                                                   const float* __restrict__ shift,
                                                   float* __restrict__ gsum,
                                                   float* __restrict__ gcnt,
                                                   int nN, int chunk) {
  const int lane = threadIdx.x & 63;
  const int wid = (blockIdx.x * blockDim.x + threadIdx.x) >> 6;
  int beg = wid * chunk;
  if (beg >= nN) return;
  int end = min(nN, beg + chunk);
  const int c2 = 2 * lane;
  float2 sc2 = *reinterpret_cast<const float2*>(scale + c2);
  float2 sh2 = *reinterpret_cast<const float2*>(shift + c2);
  int cur = -1;
  float a0 = 0.f, a1 = 0.f, cnt = 0.f;
  for (int n = beg; n < end; ++n) {
    int g = batch[n];
    if (g != cur) {
      if (cur >= 0) {
        atomicAdd(&gsum[cur * 128 + c2], a0);
        atomicAdd(&gsum[cur * 128 + c2 + 1], a1);
        if (lane == 0) atomicAdd(&gcnt[cur], cnt);
      }
      cur = g; a0 = 0.f; a1 = 0.f; cnt = 0.f;
    }
    float2 v = *reinterpret_cast<const float2*>(h + (size_t)n * 128 + c2);
    a0 += fmaxf(fmaf(v.x, sc2.x, sh2.x), 0.f);
    a1 += fmaxf(fmaf(v.y, sc2.y, sh2.y), 0.f);
    cnt += 1.f;
  }
  if (cur >= 0) {
    atomicAdd(&gsum[cur * 128 + c2], a0);
    atomicAdd(&gsum[cur * 128 + c2 + 1], a1);
    if (lane == 0) atomicAdd(&gcnt[cur], cnt);
  }
}

// ---------------- edge MLP layer1 + per-graph sum (graph-sorted, run-length regs) ----------------
__global__ __launch_bounds__(256) void edge2_kernel(const float* __restrict__ ea,
                                                    const unsigned int* __restrict__ epk,
                                                    const float* __restrict__ We1,
                                                    const float* __restrict__ be1,
                                                    float* __restrict__ esum,
                                                    float* __restrict__ ecnt,
                                                    int nE, int chunk) {
  const int lane = threadIdx.x & 63;
  const int wid = (blockIdx.x * blockDim.x + threadIdx.x) >> 6;
  int beg = wid * chunk;
  if (beg >= nE) return;
  int end = min(nE, beg + chunk);
  float w0[16], w1[16];
#pragma unroll
  for (int k = 0; k < 16; ++k) {
    w0[k] = We1[k * 128 + lane];
    w1[k] = We1[k * 128 + 64 + lane];
  }
  float b0 = be1[lane], b1 = be1[64 + lane];
  int cur = -1;
  float a0 = 0.f, a1 = 0.f, cnt = 0.f;
  for (int j = beg; j < end; ++j) {
    unsigned int pk = epk[j];
    int g = (int)(pk >> 21);
    int e = (int)(pk & 0x1FFFFFu);
    if (g != cur) {
      if (cur >= 0) {
        atomicAdd(&esum[cur * 128 + lane], a0);
        atomicAdd(&esum[cur * 128 + 64 + lane], a1);
        if (lane == 0) atomicAdd(&ecnt[cur], cnt);
      }
      cur = g; a0 = 0.f; a1 = 0.f; cnt = 0.f;
    }
    const float4* eap = reinterpret_cast<const float4*>(ea + (size_t)e * 16);
    float4 t0 = eap[0], t1 = eap[1], t2 = eap[2], t3 = eap[3];
    float u0 = b0, u1 = b1;
    u0 = fmaf(t0.x, w0[0], u0);  u1 = fmaf(t0.x, w1[0], u1);
    u0 = fmaf(t0.y, w0[1], u0);  u1 = fmaf(t0.y, w1[1], u1);
    u0 = fmaf(t0.z, w0[2], u0);  u1 = fmaf(t0.z, w1[2], u1);
    u0 = fmaf(t0.w, w0[3], u0);  u1 = fmaf(t0.w, w1[3], u1);
    u0 = fmaf(t1.x, w0[4], u0);  u1 = fmaf(t1.x, w1[4], u1);
    u0 = fmaf(t1.y, w0[5], u0);  u1 = fmaf(t1.y, w1[5], u1);
    u0 = fmaf(t1.z, w0[6], u0);  u1 = fmaf(t1.z, w1[6], u1);
    u0 = fmaf(t1.w, w0[7], u0);  u1 = fmaf(t1.w, w1[7], u1);
    u0 = fmaf(t2.x, w0[8], u0);  u1 = fmaf(t2.x, w1[8], u1);
    u0 = fmaf(t2.y, w0[9], u0);  u1 = fmaf(t2.y, w1[9], u1);
    u0 = fmaf(t2.z, w0[10], u0); u1 = fmaf(t2.z, w1[10], u1);
    u0 = fmaf(t2.w, w0[11], u0); u1 = fmaf(t2.w, w1[11], u1);
    u0 = fmaf(t3.x, w0[12], u0); u1 = fmaf(t3.x, w1[12], u1);
    u0 = fmaf(t3.y, w0[13], u0); u1 = fmaf(t3.y, w1[13], u1);
    u0 = fmaf(t3.z, w0[14], u0); u1 = fmaf(t3.z, w1[14], u1);
    u0 = fmaf(t3.w, w0[15], u0); u1 = fmaf(t3.w, w1[15], u1);
    a0 += fmaxf(u0, 0.f);
    a1 += fmaxf(u1, 0.f);
    cnt += 1.f;
  }
  if (cur >= 0) {
    atomicAdd(&esum[cur * 128 + lane], a0);
    atomicAdd(&esum[cur * 128 + 64 + lane], a1);
    if (lane == 0) atomicAdd(&ecnt[cur], cnt);
  }
}

// ---------------- final: graph_repr + edge_repr ----------------
__global__ __launch_bounds__(128) void final_kernel(const float* __restrict__ gsum,
                                                    const float* __restrict__ gcnt,
                                                    const float* __restrict__ esum,
                                                    const float* __restrict__ ecnt,
                                                    const float* __restrict__ We2,
                                                    const float* __restrict__ be2,
                                                    float* __restrict__ out) {
  __shared__ float row[128];
  int g = blockIdx.x, c = threadIdx.x;
  row[c] = esum[g * 128 + c];
  __syncthreads();
  float acc = 0.f;
#pragma unroll 4
  for (int k = 0; k < 128; ++k) acc = fmaf(row[k], We2[k * 128 + c], acc);
  float ce = ecnt[g];
  float er = (ce > 0.f) ? (acc / ce + be2[c]) : 0.f;
  float cn = gcnt[g];
  float gr = gsum[g * 128 + c] / fmaxf(cn, 1.f);
  out[g * 128 + c] = gr + er;
}

extern "C" void kernel_launch(void* const* d_in, const int* in_sizes, int n_in,
                              void* d_out, int out_size, void* d_ws, size_t ws_size,
                              hipStream_t stream) {
  const float* x    = (const float*)d_in[0];
  const int*   ei   = (const int*)d_in[1];
  const float* ea   = (const float*)d_in[2];
  const int*   bidx = (const int*)d_in[3];
  const float* Wg1  = (const float*)d_in[4];
  const float* bg1  = (const float*)d_in[5];
  const float* gm1  = (const float*)d_in[6];
  const float* bt1  = (const float*)d_in[7];
  const float* Wg2  = (const float*)d_in[8];
  const float* bg2  = (const float*)d_in[9];
  const float* gm2  = (const float*)d_in[10];
  const float* bt2  = (const float*)d_in[11];
  const float* We1  = (const float*)d_in[12];
  const float* be1  = (const float*)d_in[13];
  const float* We2  = (const float*)d_in[14];
  const float* be2  = (const float*)d_in[15];
  float* out = (float*)d_out;

  const int N = in_sizes[3];
  const int E = in_sizes[1] / 2;
  const int G = out_size / 128;
  const int* srcp = ei;
  const int* dstp = ei + E;

  char* w = (char*)d_ws;
  auto alloc = [&](size_t b) {
    char* p = w;
    w += (b + 15) & ~(size_t)15;
    return p;
  };
  float* bufB    = (float*)alloc((size_t)N * 128 * 4);           // fp32 spmm output (reused both layers)
  unsigned int* hpk = (unsigned int*)alloc((size_t)N * 64 * 4);  // packed bf16 h (entry e = ch e, e+64)
  int*   ssort   = (int*)alloc((size_t)E * 4);
  float* wgtv    = (float*)alloc((size_t)E * 4);
  unsigned int* epk = (unsigned int*)alloc((size_t)E * 4);
  int*   rp      = (int*)alloc((size_t)(N + 1) * 4);
  int*   rp2     = (int*)alloc((size_t)(N + 1) * 4);
  int*   cursor  = (int*)alloc((size_t)N * 4);
  int*   cursor2 = (int*)alloc((size_t)N * 4);
  float* dinv    = (float*)alloc((size_t)N * 4);
  char* zbase = w;
  int*   deg  = (int*)alloc((size_t)N * 4);
  int*   deg2 = (int*)alloc((size_t)N * 4);
  float* bs1  = (float*)alloc(512);
  float* bq1  = (float*)alloc(512);
  float* bs2  = (float*)alloc(512);
  float* bq2  = (float*)alloc(512);
  float* gsum = (float*)alloc((size_t)G * 128 * 4);
  float* gcnt = (float*)alloc((size_t)G * 4);
  float* esum = (float*)alloc((size_t)G * 128 * 4);
  float* ecnt = (float*)alloc((size_t)G * 4);
  int*   part  = (int*)alloc(4096);
  int*   part2 = (int*)alloc(4096);
  size_t zbytes = (size_t)(w - zbase);
  float* sc1 = (float*)alloc(512);
  float* sh1 = (float*)alloc(512);
  float* sc2 = (float*)alloc(512);
  float* sh2 = (float*)alloc(512);

  hipMemsetAsync(zbase, 0, zbytes, stream);

  (void)hipFuncSetAttribute((const void*)gemm128_kernel<false>,
                            hipFuncAttributeMaxDynamicSharedMemorySize, 73728);
  (void)hipFuncSetAttribute((const void*)gemm128_kernel<true>,
                            hipFuncAttributeMaxDynamicSharedMemorySize, 73728);

  // histograms + CSR build (dst-CSR for SpMM, src-ordered edge list for edge path)
  pre_kernel<<<(E + 255) / 256, 256, 0, stream>>>(srcp, dstp, deg, deg2, E);
  dinv_kernel<<<(N + 255) / 256, 256, 0, stream>>>(deg, dinv, N);
  int nb = (N + 1023) / 1024;
  scan1_kernel<<<nb, 256, 0, stream>>>(deg, rp, part, N);
  scan2_kernel<<<1, 1, 0, stream>>>(part, rp, nb, N);
  scan3_kernel<<<(N + 255) / 256, 256, 0, stream>>>(rp, part, cursor, N);
  scan1_kernel<<<nb, 256, 0, stream>>>(deg2, rp2, part2, N);
  scan2_kernel<<<1, 1, 0, stream>>>(part2, rp2, nb, N);
  scan3_kernel<<<(N + 255) / 256, 256, 0, stream>>>(rp2, part2, cursor2, N);
  place_kernel<<<(E + 255) / 256, 256, 0, stream>>>(srcp, dstp, bidx, dinv, cursor,
                                                    cursor2, ssort, wgtv, epk, E);

  // layer 1
  gemm128_kernel<false><<<512, 256, 73728, stream>>>(x, Wg1, nullptr, nullptr, hpk, N);
  spmm_kernel<<<2048, 256, 0, stream>>>(hpk, dinv, rp, ssort, wgtv, bg1, bufB, bs1, bq1, N);
  bnfin_kernel<<<1, 128, 0, stream>>>(bs1, bq1, gm1, bt1, sc1, sh1, 1.0f / (float)N);

  // layer 2 (BN1+ReLU fused into GEMM2's A staging)
  gemm128_kernel<true><<<512, 256, 73728, stream>>>(bufB, Wg2, sc1, sh1, hpk, N);
  spmm_kernel<<<2048, 256, 0, stream>>>(hpk, dinv, rp, ssort, wgtv, bg2, bufB, bs2, bq2, N);
  bnfin_kernel<<<1, 128, 0, stream>>>(bs2, bq2, gm2, bt2, sc2, sh2, 1.0f / (float)N);

  // pooling (BN2+ReLU fused) + edge path + output
  int nwp = (2048 * 256) / 64;
  int chunkN = (N + nwp - 1) / nwp;
  pool_kernel<<<2048, 256, 0, stream>>>(bufB, bidx, sc2, sh2, gsum, gcnt, N, chunkN);
  int nwe = (2048 * 256) / 64;
  int chunkE = (E + nwe - 1) / nwe;
  edge2_kernel<<<2048, 256, 0, stream>>>(ea, epk, We1, be1, esum, ecnt, E, chunkE);
  final_kernel<<<G, 128, 0, stream>>>(gsum, gcnt, esum, ecnt, We2, be2, out);
}

// Round 6
// 1527.000 us; speedup vs baseline: 2.0380x; 2.0380x over previous
//
#include <hip/hip_runtime.h>
#include <cstdint>

// ---- bf16 pack/unpack helpers (RNE) ----
__device__ inline unsigned int bfpack2(float a, float b) {
  unsigned int ua = __float_as_uint(a), ub = __float_as_uint(b);
  ua += 0x7FFFu + ((ua >> 16) & 1u);
  ub += 0x7FFFu + ((ub >> 16) & 1u);
  return (ua >> 16) | (ub & 0xFFFF0000u);
}
__device__ inline float bflo(unsigned int u) { return __uint_as_float(u << 16); }
__device__ inline float bfhi(unsigned int u) { return __uint_as_float(u & 0xFFFF0000u); }

// ---------------- degree histograms (dst for GCN norm, src for edge sort) ----------------
__global__ __launch_bounds__(256) void pre_kernel(const int* __restrict__ src,
                                                  const int* __restrict__ dst,
                                                  int* __restrict__ deg,
                                                  int* __restrict__ deg2, int nE) {
  int e = blockIdx.x * 256 + threadIdx.x;
  if (e < nE) {
    atomicAdd(&deg[dst[e]], 1);
    atomicAdd(&deg2[src[e]], 1);
  }
}

__global__ __launch_bounds__(256) void dinv_kernel(const int* __restrict__ deg,
                                                   float* __restrict__ dinv, int n) {
  int i = blockIdx.x * 256 + threadIdx.x;
  if (i < n) dinv[i] = rsqrtf((float)deg[i] + 1.0f);
}

// ---------------- exclusive scan (3 kernels) ----------------
// pad != 0: scan (deg+7)&~7 instead of deg (8-aligned CSR rows).
__global__ __launch_bounds__(256) void scan1_kernel(const int* __restrict__ deg,
                                                    int* __restrict__ rp,
                                                    int* __restrict__ part, int n, int pad) {
  __shared__ int sh[256];
  int b = blockIdx.x, t = threadIdx.x;
  int base = b * 1024 + t * 4;
  int v0 = (base + 0 < n) ? deg[base + 0] : 0;
  int v1 = (base + 1 < n) ? deg[base + 1] : 0;
  int v2 = (base + 2 < n) ? deg[base + 2] : 0;
  int v3 = (base + 3 < n) ? deg[base + 3] : 0;
  if (pad) {
    v0 = (v0 + 7) & ~7; v1 = (v1 + 7) & ~7;
    v2 = (v2 + 7) & ~7; v3 = (v3 + 7) & ~7;
  }
  int ts = v0 + v1 + v2 + v3;
  sh[t] = ts;
  __syncthreads();
  for (int off = 1; off < 256; off <<= 1) {
    int x = (t >= off) ? sh[t - off] : 0;
    __syncthreads();
    sh[t] += x;
    __syncthreads();
  }
  int excl = sh[t] - ts;
  if (t == 255) part[b] = sh[255];
  if (base + 0 < n) rp[base + 0] = excl;
  if (base + 1 < n) rp[base + 1] = excl + v0;
  if (base + 2 < n) rp[base + 2] = excl + v0 + v1;
  if (base + 3 < n) rp[base + 3] = excl + v0 + v1 + v2;
}

__global__ void scan2_kernel(int* part, int* rp, int nb, int n) {
  if (blockIdx.x == 0 && threadIdx.x == 0) {
    int run = 0;
    for (int i = 0; i < nb; ++i) { int v = part[i]; part[i] = run; run += v; }
    rp[n] = run;
  }
}

__global__ __launch_bounds__(256) void scan3_kernel(int* __restrict__ rp,
                                                    const int* __restrict__ part,
                                                    int* __restrict__ cursor, int n) {
  int i = blockIdx.x * 256 + threadIdx.x;
  if (i < n) {
    int v = rp[i] + part[i >> 10];
    rp[i] = v;
    cursor[i] = v;
  }
}

// ---------------- CSR placement: dst-CSR (srcs+wgt per node) + src-ordered edge list ----------------
__global__ __launch_bounds__(256) void place_kernel(const int* __restrict__ src,
                                                    const int* __restrict__ dst,
                                                    const int* __restrict__ batch,
                                                    const float* __restrict__ dinv,
                                                    int* __restrict__ cursor,
                                                    int* __restrict__ cursor2,
                                                    int* __restrict__ ssort,
                                                    float* __restrict__ wgtv,
                                                    unsigned int* __restrict__ epk, int nE) {
  int e = blockIdx.x * 256 + threadIdx.x;
  if (e < nE) {
    int s = src[e];
    int d = dst[e];
    int p1 = atomicAdd(&cursor[d], 1);
    ssort[p1] = s;
    wgtv[p1] = dinv[s] * dinv[d];
    int g = batch[s];
    int p2 = atomicAdd(&cursor2[s], 1);
    epk[p2] = ((unsigned int)g << 21) | (unsigned int)e;
  }
}

// fill pad slots [rp[i]+deg[i], rp[i+1]) with src=i, w=0 (no-op edges)
__global__ __launch_bounds__(256) void pad_kernel(const int* __restrict__ rp,
                                                  const int* __restrict__ deg,
                                                  int* __restrict__ ssort,
                                                  float* __restrict__ wgtv, int nN) {
  int i = blockIdx.x * 256 + threadIdx.x;
  if (i < nN) {
    int b = rp[i] + deg[i], e = rp[i + 1];
    for (int k = b; k < e; ++k) { ssort[k] = i; wgtv[k] = 0.f; }
  }
}

// ---------------- dense GEMM: hpk[N,64] = pack_bf16(act(A)[N,128] @ W[128,128]) ----------------
// Output written ONLY as packed bf162: entry e of a row holds channels (e, e+64).
// FUSED applies y = relu(a*scale+shift) while staging A (previous layer's BN+ReLU).
template <bool FUSED>
__global__ __launch_bounds__(256) void gemm128_kernel(const float* __restrict__ A,
                                                      const float* __restrict__ W,
                                                      const float* __restrict__ scale,
                                                      const float* __restrict__ shift,
                                                      unsigned int* __restrict__ hpk,
                                                      int nrows) {
  extern __shared__ float lds[];
  float* Ws = lds;             // 128*128 floats
  float* xs = lds + 128 * 128; // 16*128 floats
  const int t = threadIdx.x;
  for (int i = t; i < (128 * 128) / 4; i += 256)
    reinterpret_cast<float4*>(Ws)[i] = reinterpret_cast<const float4*>(W)[i];
  const int wave = t >> 6, lane = t & 63;
  for (int rb = blockIdx.x * 16; rb < nrows; rb += gridDim.x * 16) {
    int nr = min(16, nrows - rb);
    __syncthreads();
    for (int i = t; i < nr * 32; i += 256) {
      float4 v = reinterpret_cast<const float4*>(A + (size_t)rb * 128)[i];
      if (FUSED) {
        float4 sc4 = reinterpret_cast<const float4*>(scale)[i & 31];
        float4 sh4 = reinterpret_cast<const float4*>(shift)[i & 31];
        v.x = fmaxf(fmaf(v.x, sc4.x, sh4.x), 0.f);
        v.y = fmaxf(fmaf(v.y, sc4.y, sh4.y), 0.f);
        v.z = fmaxf(fmaf(v.z, sc4.z, sh4.z), 0.f);
        v.w = fmaxf(fmaf(v.w, sc4.w, sh4.w), 0.f);
      }
      reinterpret_cast<float4*>(xs)[i] = v;
    }
    __syncthreads();
    float acc[4][2] = {{0.f, 0.f}, {0.f, 0.f}, {0.f, 0.f}, {0.f, 0.f}};
    const float* xw = xs + wave * 4 * 128;
#pragma unroll 4
    for (int k = 0; k < 128; ++k) {
      float w0 = Ws[k * 128 + lane];
      float w1 = Ws[k * 128 + 64 + lane];
#pragma unroll
      for (int r = 0; r < 4; ++r) {
        float a = xw[r * 128 + k];
        acc[r][0] = fmaf(a, w0, acc[r][0]);
        acc[r][1] = fmaf(a, w1, acc[r][1]);
      }
    }
#pragma unroll
    for (int r = 0; r < 4; ++r) {
      int row = rb + wave * 4 + r;
      if (row < nrows)
        hpk[(size_t)row * 64 + lane] = bfpack2(acc[r][0], acc[r][1]);
    }
  }
}

// ---------------- SpMM + self-loop + bias, with BN stats ----------------
// Wave per node, lane = channels (l, 64+l). Edge lists are 8-padded: the inner
// loop is always full 8-edge batches -> int4x2/float4x2 index+weight loads and
// 8 INDEPENDENT 256B row-gathers in flight per iteration. No shuffles, no tail.
__global__ __launch_bounds__(256) void spmm_kernel(const unsigned int* __restrict__ hpk,
                                                   const float* __restrict__ dinv,
                                                   const int* __restrict__ rp,
                                                   const int* __restrict__ srcs,
                                                   const float* __restrict__ wgtv,
                                                   const float* __restrict__ bias,
                                                   float* __restrict__ outp,
                                                   float* __restrict__ bnsum,
                                                   float* __restrict__ bnsq, int nN) {
  const int lane = threadIdx.x & 63;
  const int wid = (blockIdx.x * blockDim.x + threadIdx.x) >> 6;
  const int nw = (gridDim.x * blockDim.x) >> 6;
  float b0 = bias[lane], b1 = bias[64 + lane];
  float s0 = 0.f, s1 = 0.f, q0 = 0.f, q1 = 0.f;
  for (int n = wid; n < nN; n += nw) {
    const int beg = rp[n], end = rp[n + 1];
    float aA0 = 0.f, aA1 = 0.f, aB0 = 0.f, aB1 = 0.f;
    for (int j = beg; j < end; j += 8) {
      int4 ia = reinterpret_cast<const int4*>(srcs + j)[0];
      int4 ib = reinterpret_cast<const int4*>(srcs + j)[1];
      float4 wa = reinterpret_cast<const float4*>(wgtv + j)[0];
      float4 wb = reinterpret_cast<const float4*>(wgtv + j)[1];
      unsigned int p0 = hpk[(size_t)ia.x * 64 + lane];
      unsigned int p1 = hpk[(size_t)ia.y * 64 + lane];
      unsigned int p2 = hpk[(size_t)ia.z * 64 + lane];
      unsigned int p3 = hpk[(size_t)ia.w * 64 + lane];
      unsigned int p4 = hpk[(size_t)ib.x * 64 + lane];
      unsigned int p5 = hpk[(size_t)ib.y * 64 + lane];
      unsigned int p6 = hpk[(size_t)ib.z * 64 + lane];
      unsigned int p7 = hpk[(size_t)ib.w * 64 + lane];
      aA0 = fmaf(wa.x, bflo(p0), aA0); aA1 = fmaf(wa.x, bfhi(p0), aA1);
      aB0 = fmaf(wa.y, bflo(p1), aB0); aB1 = fmaf(wa.y, bfhi(p1), aB1);
      aA0 = fmaf(wa.z, bflo(p2), aA0); aA1 = fmaf(wa.z, bfhi(p2), aA1);
      aB0 = fmaf(wa.w, bflo(p3), aB0); aB1 = fmaf(wa.w, bfhi(p3), aB1);
      aA0 = fmaf(wb.x, bflo(p4), aA0); aA1 = fmaf(wb.x, bfhi(p4), aA1);
      aB0 = fmaf(wb.y, bflo(p5), aB0); aB1 = fmaf(wb.y, bfhi(p5), aB1);
      aA0 = fmaf(wb.z, bflo(p6), aA0); aA1 = fmaf(wb.z, bfhi(p6), aA1);
      aB0 = fmaf(wb.w, bflo(p7), aB0); aB1 = fmaf(wb.w, bfhi(p7), aB1);
    }
    float a0 = aA0 + aB0, a1 = aA1 + aB1;
    float dn = dinv[n];
    float sw = dn * dn;
    unsigned int pn = hpk[(size_t)n * 64 + lane];
    float o0 = fmaf(bflo(pn), sw, a0) + b0;
    float o1 = fmaf(bfhi(pn), sw, a1) + b1;
    outp[(size_t)n * 128 + lane] = o0;
    outp[(size_t)n * 128 + 64 + lane] = o1;
    s0 += o0; s1 += o1;
    q0 = fmaf(o0, o0, q0); q1 = fmaf(o1, o1, q1);
  }
  atomicAdd(&bnsum[lane], s0);
  atomicAdd(&bnsum[64 + lane], s1);
  atomicAdd(&bnsq[lane], q0);
  atomicAdd(&bnsq[64 + lane], q1);
}

// ---------------- BN finalize ----------------
__global__ void bnfin_kernel(const float* __restrict__ sum, const float* __restrict__ sq,
                             const float* __restrict__ gamma, const float* __restrict__ beta,
                             float* __restrict__ scale, float* __restrict__ shift,
                             float invN) {
  int c = threadIdx.x;
  float mu = sum[c] * invN;
  float var = sq[c] * invN - mu * mu;
  float sc = gamma[c] * rsqrtf(var + 1e-5f);
  scale[c] = sc;
  shift[c] = beta[c] - mu * sc;
}

// ---------------- graph mean pool, fused BN+ReLU (batch_idx sorted -> run-length) ----------------
__global__ __launch_bounds__(256) void pool_kernel(const float* __restrict__ h,
                                                   const int* __restrict__ batch,
                                                   const float* __restrict__ scale,
                                                   const float* __restrict__ shift,
                                                   float* __restrict__ gsum,
                                                   float* __restrict__ gcnt,
                                                   int nN, int chunk) {
  const int lane = threadIdx.x & 63;
  const int wid = (blockIdx.x * blockDim.x + threadIdx.x) >> 6;
  int beg = wid * chunk;
  if (beg >= nN) return;
  int end = min(nN, beg + chunk);
  const int c2 = 2 * lane;
  float2 sc2 = *reinterpret_cast<const float2*>(scale + c2);
  float2 sh2 = *reinterpret_cast<const float2*>(shift + c2);
  int cur = -1;
  float a0 = 0.f, a1 = 0.f, cnt = 0.f;
  for (int n = beg; n < end; ++n) {
    int g = batch[n];
    if (g != cur) {
      if (cur >= 0) {
        atomicAdd(&gsum[cur * 128 + c2], a0);
        atomicAdd(&gsum[cur * 128 + c2 + 1], a1);
        if (lane == 0) atomicAdd(&gcnt[cur], cnt);
      }
      cur = g; a0 = 0.f; a1 = 0.f; cnt = 0.f;
    }
    float2 v = *reinterpret_cast<const float2*>(h + (size_t)n * 128 + c2);
    a0 += fmaxf(fmaf(v.x, sc2.x, sh2.x), 0.f);
    a1 += fmaxf(fmaf(v.y, sc2.y, sh2.y), 0.f);
    cnt += 1.f;
  }
  if (cur >= 0) {
    atomicAdd(&gsum[cur * 128 + c2], a0);
    atomicAdd(&gsum[cur * 128 + c2 + 1], a1);
    if (lane == 0) atomicAdd(&gcnt[cur], cnt);
  }
}

// ---------------- edge MLP layer1 + per-graph sum (graph-sorted, run-length regs) ----------------
__global__ __launch_bounds__(256) void edge2_kernel(const float* __restrict__ ea,
                                                    const unsigned int* __restrict__ epk,
                                                    const float* __restrict__ We1,
                                                    const float* __restrict__ be1,
                                                    float* __restrict__ esum,
                                                    float* __restrict__ ecnt,
                                                    int nE, int chunk) {
  const int lane = threadIdx.x & 63;
  const int wid = (blockIdx.x * blockDim.x + threadIdx.x) >> 6;
  int beg = wid * chunk;
  if (beg >= nE) return;
  int end = min(nE, beg + chunk);
  float w0[16], w1[16];
#pragma unroll
  for (int k = 0; k < 16; ++k) {
    w0[k] = We1[k * 128 + lane];
    w1[k] = We1[k * 128 + 64 + lane];
  }
  float b0 = be1[lane], b1 = be1[64 + lane];
  int cur = -1;
  float a0 = 0.f, a1 = 0.f, cnt = 0.f;
  for (int j = beg; j < end; ++j) {
    unsigned int pk = epk[j];
    int g = (int)(pk >> 21);
    int e = (int)(pk & 0x1FFFFFu);
    if (g != cur) {
      if (cur >= 0) {
        atomicAdd(&esum[cur * 128 + lane], a0);
        atomicAdd(&esum[cur * 128 + 64 + lane], a1);
        if (lane == 0) atomicAdd(&ecnt[cur], cnt);
      }
      cur = g; a0 = 0.f; a1 = 0.f; cnt = 0.f;
    }
    const float4* eap = reinterpret_cast<const float4*>(ea + (size_t)e * 16);
    float4 t0 = eap[0], t1 = eap[1], t2 = eap[2], t3 = eap[3];
    float u0 = b0, u1 = b1;
    u0 = fmaf(t0.x, w0[0], u0);  u1 = fmaf(t0.x, w1[0], u1);
    u0 = fmaf(t0.y, w0[1], u0);  u1 = fmaf(t0.y, w1[1], u1);
    u0 = fmaf(t0.z, w0[2], u0);  u1 = fmaf(t0.z, w1[2], u1);
    u0 = fmaf(t0.w, w0[3], u0);  u1 = fmaf(t0.w, w1[3], u1);
    u0 = fmaf(t1.x, w0[4], u0);  u1 = fmaf(t1.x, w1[4], u1);
    u0 = fmaf(t1.y, w0[5], u0);  u1 = fmaf(t1.y, w1[5], u1);
    u0 = fmaf(t1.z, w0[6], u0);  u1 = fmaf(t1.z, w1[6], u1);
    u0 = fmaf(t1.w, w0[7], u0);  u1 = fmaf(t1.w, w1[7], u1);
    u0 = fmaf(t2.x, w0[8], u0);  u1 = fmaf(t2.x, w1[8], u1);
    u0 = fmaf(t2.y, w0[9], u0);  u1 = fmaf(t2.y, w1[9], u1);
    u0 = fmaf(t2.z, w0[10], u0); u1 = fmaf(t2.z, w1[10], u1);
    u0 = fmaf(t2.w, w0[11], u0); u1 = fmaf(t2.w, w1[11], u1);
    u0 = fmaf(t3.x, w0[12], u0); u1 = fmaf(t3.x, w1[12], u1);
    u0 = fmaf(t3.y, w0[13], u0); u1 = fmaf(t3.y, w1[13], u1);
    u0 = fmaf(t3.z, w0[14], u0); u1 = fmaf(t3.z, w1[14], u1);
    u0 = fmaf(t3.w, w0[15], u0); u1 = fmaf(t3.w, w1[15], u1);
    a0 += fmaxf(u0, 0.f);
    a1 += fmaxf(u1, 0.f);
    cnt += 1.f;
  }
  if (cur >= 0) {
    atomicAdd(&esum[cur * 128 + lane], a0);
    atomicAdd(&esum[cur * 128 + 64 + lane], a1);
    if (lane == 0) atomicAdd(&ecnt[cur], cnt);
  }
}

// ---------------- final: graph_repr + edge_repr ----------------
__global__ __launch_bounds__(128) void final_kernel(const float* __restrict__ gsum,
                                                    const float* __restrict__ gcnt,
                                                    const float* __restrict__ esum,
                                                    const float* __restrict__ ecnt,
                                                    const float* __restrict__ We2,
                                                    const float* __restrict__ be2,
                                                    float* __restrict__ out) {
  __shared__ float row[128];
  int g = blockIdx.x, c = threadIdx.x;
  row[c] = esum[g * 128 + c];
  __syncthreads();
  float acc = 0.f;
#pragma unroll 4
  for (int k = 0; k < 128; ++k) acc = fmaf(row[k], We2[k * 128 + c], acc);
  float ce = ecnt[g];
  float er = (ce > 0.f) ? (acc / ce + be2[c]) : 0.f;
  float cn = gcnt[g];
  float gr = gsum[g * 128 + c] / fmaxf(cn, 1.f);
  out[g * 128 + c] = gr + er;
}

extern "C" void kernel_launch(void* const* d_in, const int* in_sizes, int n_in,
                              void* d_out, int out_size, void* d_ws, size_t ws_size,
                              hipStream_t stream) {
  const float* x    = (const float*)d_in[0];
  const int*   ei   = (const int*)d_in[1];
  const float* ea   = (const float*)d_in[2];
  const int*   bidx = (const int*)d_in[3];
  const float* Wg1  = (const float*)d_in[4];
  const float* bg1  = (const float*)d_in[5];
  const float* gm1  = (const float*)d_in[6];
  const float* bt1  = (const float*)d_in[7];
  const float* Wg2  = (const float*)d_in[8];
  const float* bg2  = (const float*)d_in[9];
  const float* gm2  = (const float*)d_in[10];
  const float* bt2  = (const float*)d_in[11];
  const float* We1  = (const float*)d_in[12];
  const float* be1  = (const float*)d_in[13];
  const float* We2  = (const float*)d_in[14];
  const float* be2  = (const float*)d_in[15];
  float* out = (float*)d_out;

  const int N = in_sizes[3];
  const int E = in_sizes[1] / 2;
  const int G = out_size / 128;
  const int* srcp = ei;
  const int* dstp = ei + E;
  const int Epad = E + 8 * N;  // upper bound on padded CSR slots

  char* w = (char*)d_ws;
  auto alloc = [&](size_t b) {
    char* p = w;
    w += (b + 15) & ~(size_t)15;
    return p;
  };
  float* bufB    = (float*)alloc((size_t)N * 128 * 4);           // fp32 spmm output (reused both layers)
  unsigned int* hpk = (unsigned int*)alloc((size_t)N * 64 * 4);  // packed bf16 h (entry e = ch e, e+64)
  int*   ssort   = (int*)alloc((size_t)Epad * 4);
  float* wgtv    = (float*)alloc((size_t)Epad * 4);
  unsigned int* epk = (unsigned int*)alloc((size_t)E * 4);
  int*   rp      = (int*)alloc((size_t)(N + 1) * 4);
  int*   rp2     = (int*)alloc((size_t)(N + 1) * 4);
  int*   cursor  = (int*)alloc((size_t)N * 4);
  int*   cursor2 = (int*)alloc((size_t)N * 4);
  float* dinv    = (float*)alloc((size_t)N * 4);
  char* zbase = w;
  int*   deg  = (int*)alloc((size_t)N * 4);
  int*   deg2 = (int*)alloc((size_t)N * 4);
  float* bs1  = (float*)alloc(512);
  float* bq1  = (float*)alloc(512);
  float* bs2  = (float*)alloc(512);
  float* bq2  = (float*)alloc(512);
  float* gsum = (float*)alloc((size_t)G * 128 * 4);
  float* gcnt = (float*)alloc((size_t)G * 4);
  float* esum = (float*)alloc((size_t)G * 128 * 4);
  float* ecnt = (float*)alloc((size_t)G * 4);
  int*   part  = (int*)alloc(4096);
  int*   part2 = (int*)alloc(4096);
  size_t zbytes = (size_t)(w - zbase);
  float* sc1 = (float*)alloc(512);
  float* sh1 = (float*)alloc(512);
  float* sc2 = (float*)alloc(512);
  float* sh2 = (float*)alloc(512);

  hipMemsetAsync(zbase, 0, zbytes, stream);

  (void)hipFuncSetAttribute((const void*)gemm128_kernel<false>,
                            hipFuncAttributeMaxDynamicSharedMemorySize, 73728);
  (void)hipFuncSetAttribute((const void*)gemm128_kernel<true>,
                            hipFuncAttributeMaxDynamicSharedMemorySize, 73728);

  // histograms + CSR build (8-padded dst-CSR for SpMM, src-ordered edge list for edge path)
  pre_kernel<<<(E + 255) / 256, 256, 0, stream>>>(srcp, dstp, deg, deg2, E);
  dinv_kernel<<<(N + 255) / 256, 256, 0, stream>>>(deg, dinv, N);
  int nb = (N + 1023) / 1024;
  scan1_kernel<<<nb, 256, 0, stream>>>(deg, rp, part, N, 1);
  scan2_kernel<<<1, 1, 0, stream>>>(part, rp, nb, N);
  scan3_kernel<<<(N + 255) / 256, 256, 0, stream>>>(rp, part, cursor, N);
  scan1_kernel<<<nb, 256, 0, stream>>>(deg2, rp2, part2, N, 0);
  scan2_kernel<<<1, 1, 0, stream>>>(part2, rp2, nb, N);
  scan3_kernel<<<(N + 255) / 256, 256, 0, stream>>>(rp2, part2, cursor2, N);
  place_kernel<<<(E + 255) / 256, 256, 0, stream>>>(srcp, dstp, bidx, dinv, cursor,
                                                    cursor2, ssort, wgtv, epk, E);
  pad_kernel<<<(N + 255) / 256, 256, 0, stream>>>(rp, deg, ssort, wgtv, N);

  // layer 1
  gemm128_kernel<false><<<512, 256, 73728, stream>>>(x, Wg1, nullptr, nullptr, hpk, N);
  spmm_kernel<<<2048, 256, 0, stream>>>(hpk, dinv, rp, ssort, wgtv, bg1, bufB, bs1, bq1, N);
  bnfin_kernel<<<1, 128, 0, stream>>>(bs1, bq1, gm1, bt1, sc1, sh1, 1.0f / (float)N);

  // layer 2 (BN1+ReLU fused into GEMM2's A staging)
  gemm128_kernel<true><<<512, 256, 73728, stream>>>(bufB, Wg2, sc1, sh1, hpk, N);
  spmm_kernel<<<2048, 256, 0, stream>>>(hpk, dinv, rp, ssort, wgtv, bg2, bufB, bs2, bq2, N);
  bnfin_kernel<<<1, 128, 0, stream>>>(bs2, bq2, gm2, bt2, sc2, sh2, 1.0f / (float)N);

  // pooling (BN2+ReLU fused) + edge path + output
  int nwp = (2048 * 256) / 64;
  int chunkN = (N + nwp - 1) / nwp;
  pool_kernel<<<2048, 256, 0, stream>>>(bufB, bidx, sc2, sh2, gsum, gcnt, N, chunkN);
  int nwe = (2048 * 256) / 64;
  int chunkE = (E + nwe - 1) / nwe;
  edge2_kernel<<<2048, 256, 0, stream>>>(ea, epk, We1, be1, esum, ecnt, E, chunkE);
  final_kernel<<<G, 128, 0, stream>>>(gsum, gcnt, esum, ecnt, We2, be2, out);
}